// Round 1
// baseline (722.922 us; speedup 1.0000x reference)
//
#include <hip/hip_runtime.h>
#include <hip/hip_bf16.h>
#include <math.h>

typedef __bf16 bf16_t;
typedef __bf16 bf16x8 __attribute__((ext_vector_type(8)));
typedef __bf16 bf16x4 __attribute__((ext_vector_type(4)));
typedef float  f32x4  __attribute__((ext_vector_type(4)));

#define B_   8
#define L_   1024
#define D_   512
#define H_   8
#define HD_  4096   // H*D
#define BL_  8192   // B*L

__device__ __forceinline__ void gload_lds16(const bf16_t* g, bf16_t* l) {
  __builtin_amdgcn_global_load_lds(
      (const __attribute__((address_space(1))) unsigned int*)g,
      (__attribute__((address_space(3))) unsigned int*)l,
      16, 0, 0);
}

// ---------------- fp32 -> bf16 convert (vectorized) ----------------
__global__ void f2b(const float4* __restrict__ s, bf16x4* __restrict__ d, int n4) {
  int i = blockIdx.x * blockDim.x + threadIdx.x;
  if (i >= n4) return;
  float4 v = s[i];
  bf16x4 o;
  o[0] = (bf16_t)v.x; o[1] = (bf16_t)v.y; o[2] = (bf16_t)v.z; o[3] = (bf16_t)v.w;
  d[i] = o;
}

// ---------------- transpose + convert fp32(R,C) -> bf16(C,R) ----------------
__global__ void tconv(const float* __restrict__ s, bf16_t* __restrict__ d, int R, int C) {
  __shared__ float t[32][33];
  int c0 = blockIdx.x * 32, r0 = blockIdx.y * 32;
  int tx = threadIdx.x, ty = threadIdx.y;
  #pragma unroll
  for (int i = 0; i < 32; i += 8)
    t[ty + i][tx] = s[(long)(r0 + ty + i) * C + c0 + tx];
  __syncthreads();
  #pragma unroll
  for (int i = 0; i < 32; i += 8)
    d[(long)(c0 + ty + i) * R + r0 + tx] = (bf16_t)t[tx][ty + i];
}

// ------- per-(b,h) transpose bf16: vh_flat(8192,4096) -> vhT[bz](512,1024) -------
__global__ void tbf(const bf16_t* __restrict__ s, bf16_t* __restrict__ d) {
  __shared__ bf16_t t[32][33];
  int bz = blockIdx.z; int b = bz >> 3, h = bz & 7;
  const bf16_t* S = s + (long)b * L_ * HD_ + (long)h * D_;
  bf16_t* Dp = d + (long)bz * D_ * L_;
  int l0 = blockIdx.y * 32, d0 = blockIdx.x * 32;
  int tx = threadIdx.x, ty = threadIdx.y;
  #pragma unroll
  for (int i = 0; i < 32; i += 8)
    t[ty + i][tx] = S[(long)(l0 + ty + i) * HD_ + d0 + tx];
  __syncthreads();
  #pragma unroll
  for (int i = 0; i < 32; i += 8)
    Dp[(long)(d0 + ty + i) * L_ + l0 + tx] = t[tx][ty + i];
}

// ---------------- bf16 GEMM, A(M,K) x Bt(N,K)^T, 128x128 tile, BK=64 ----------------
// EPI 0: bf16 store; EPI 1: f32 store; EPI 2: f32 store + residual add
template<int EPI>
__launch_bounds__(256, 2)
__global__ void gemm_bt(const bf16_t* __restrict__ A, long sAb, long sAh, int lda,
                        const bf16_t* __restrict__ Bt, long sBb, long sBh, int ldb,
                        void* __restrict__ Cv, long sCb, long sCh, int ldc,
                        int K, float scale, const float* __restrict__ res)
{
  __shared__ bf16_t sA[128 * 64];
  __shared__ bf16_t sB[128 * 64];
  const int bz = blockIdx.z, b = bz >> 3, h = bz & 7;
  A  += (long)b * sAb + (long)h * sAh;
  Bt += (long)b * sBb + (long)h * sBh;
  const int m0 = blockIdx.y * 128, n0 = blockIdx.x * 128;
  const int tid = threadIdx.x, lane = tid & 63, wid = tid >> 6;
  const int waveM = wid >> 1, waveN = wid & 1;
  f32x4 acc[4][4] = {};
  // staging map: issue j, wave wid: rows (j*4+wid)*8 + lane/8, k-inner (lane%8)*8
  const int srow = wid * 8 + (lane >> 3);
  const int skin = (lane & 7) * 8;
  const bf16_t* Ag = A + (long)(m0 + srow) * lda + skin;
  const bf16_t* Bg = Bt + (long)(n0 + srow) * ldb + skin;
  for (int k0 = 0; k0 < K; k0 += 64) {
    #pragma unroll
    for (int j = 0; j < 4; ++j) {
      gload_lds16(Ag + (long)(j * 32) * lda + k0, sA + (j * 4 + wid) * 512);
      gload_lds16(Bg + (long)(j * 32) * ldb + k0, sB + (j * 4 + wid) * 512);
    }
    __syncthreads();   // drains vmcnt -> LDS writes visible
    #pragma unroll
    for (int kk = 0; kk < 2; ++kk) {
      bf16x8 af[4], bfr[4];
      #pragma unroll
      for (int i = 0; i < 4; ++i) {
        af[i]  = *(const bf16x8*)(sA + (waveM * 64 + i * 16 + (lane & 15)) * 64 + kk * 32 + ((lane >> 4) * 8));
        bfr[i] = *(const bf16x8*)(sB + (waveN * 64 + i * 16 + (lane & 15)) * 64 + kk * 32 + ((lane >> 4) * 8));
      }
      #pragma unroll
      for (int i = 0; i < 4; ++i)
        #pragma unroll
        for (int j = 0; j < 4; ++j)
          acc[i][j] = __builtin_amdgcn_mfma_f32_16x16x32_bf16(af[i], bfr[j], acc[i][j], 0, 0, 0);
    }
    __syncthreads();   // compute done before next-tile overwrite
  }
  const long coff = (long)b * sCb + (long)h * sCh;
  #pragma unroll
  for (int i = 0; i < 4; ++i) {
    const int rbase = m0 + waveM * 64 + i * 16 + ((lane >> 4) << 2);
    #pragma unroll
    for (int j = 0; j < 4; ++j) {
      const int c = n0 + waveN * 64 + j * 16 + (lane & 15);
      #pragma unroll
      for (int r = 0; r < 4; ++r) {
        float v = acc[i][j][r] * scale;
        long idx = coff + (long)(rbase + r) * ldc + c;
        if (EPI == 0)      ((bf16_t*)Cv)[idx] = (bf16_t)v;
        else if (EPI == 1) ((float*)Cv)[idx] = v;
        else               ((float*)Cv)[idx] = v + res[(long)(rbase + r) * ldc + c];
      }
    }
  }
}

// ---------------- softmax: one wave per 1024-col row, in-place f32 + bf16 copy ----------------
__global__ void softmax_rows(float* __restrict__ attn, bf16_t* __restrict__ abf) {
  const long row = (long)blockIdx.x * 4 + (threadIdx.x >> 6);
  const int lane = threadIdx.x & 63;
  float* p = attn + row * 1024;
  float4 v[4];
  float m = -1e30f;
  #pragma unroll
  for (int j = 0; j < 4; ++j) {
    v[j] = ((const float4*)p)[j * 64 + lane];
    m = fmaxf(m, fmaxf(fmaxf(v[j].x, v[j].y), fmaxf(v[j].z, v[j].w)));
  }
  #pragma unroll
  for (int o = 32; o; o >>= 1) m = fmaxf(m, __shfl_xor(m, o));
  float s = 0.f;
  #pragma unroll
  for (int j = 0; j < 4; ++j) {
    v[j].x = expf(v[j].x - m); v[j].y = expf(v[j].y - m);
    v[j].z = expf(v[j].z - m); v[j].w = expf(v[j].w - m);
    s += v[j].x + v[j].y + v[j].z + v[j].w;
  }
  #pragma unroll
  for (int o = 32; o; o >>= 1) s += __shfl_xor(s, o);
  const float inv = 1.f / s;
  bf16x4* ab = (bf16x4*)(abf + row * 1024);
  #pragma unroll
  for (int j = 0; j < 4; ++j) {
    v[j].x *= inv; v[j].y *= inv; v[j].z *= inv; v[j].w *= inv;
    ((float4*)p)[j * 64 + lane] = v[j];
    bf16x4 o4;
    o4[0] = (bf16_t)v[j].x; o4[1] = (bf16_t)v[j].y;
    o4[2] = (bf16_t)v[j].z; o4[3] = (bf16_t)v[j].w;
    ab[j * 64 + lane] = o4;
  }
}

// ---------------- LayerNorm: one wave per 512-col row, in-place ----------------
__global__ void ln_rows(float* __restrict__ o, const float* __restrict__ g,
                        const float* __restrict__ be) {
  const long row = (long)blockIdx.x * 4 + (threadIdx.x >> 6);
  const int lane = threadIdx.x & 63;
  float* p = o + row * 512;
  float4 a = ((const float4*)p)[lane];
  float4 b = ((const float4*)p)[lane + 64];
  float s  = a.x + a.y + a.z + a.w + b.x + b.y + b.z + b.w;
  float s2 = a.x*a.x + a.y*a.y + a.z*a.z + a.w*a.w
           + b.x*b.x + b.y*b.y + b.z*b.z + b.w*b.w;
  #pragma unroll
  for (int t = 32; t; t >>= 1) { s += __shfl_xor(s, t); s2 += __shfl_xor(s2, t); }
  const float mu  = s * (1.f / 512.f);
  const float var = s2 * (1.f / 512.f) - mu * mu;
  const float inv = rsqrtf(var + 1e-6f);
  float4 g0 = ((const float4*)g)[lane],  g1 = ((const float4*)g)[lane + 64];
  float4 b0 = ((const float4*)be)[lane], b1 = ((const float4*)be)[lane + 64];
  a.x = (a.x - mu) * inv * g0.x + b0.x;  a.y = (a.y - mu) * inv * g0.y + b0.y;
  a.z = (a.z - mu) * inv * g0.z + b0.z;  a.w = (a.w - mu) * inv * g0.w + b0.w;
  b.x = (b.x - mu) * inv * g1.x + b1.x;  b.y = (b.y - mu) * inv * g1.y + b1.y;
  b.z = (b.z - mu) * inv * g1.z + b1.z;  b.w = (b.w - mu) * inv * g1.w + b1.w;
  ((float4*)p)[lane] = a;
  ((float4*)p)[lane + 64] = b;
}

extern "C" void kernel_launch(void* const* d_in, const int* in_sizes, int n_in,
                              void* d_out, int out_size, void* d_ws, size_t ws_size,
                              hipStream_t stream) {
  const float* q   = (const float*)d_in[0];
  const float* k   = (const float*)d_in[1];
  const float* v   = (const float*)d_in[2];
  const float* wq  = (const float*)d_in[3];
  const float* wk  = (const float*)d_in[4];
  const float* wv  = (const float*)d_in[5];
  const float* wfc = (const float*)d_in[6];
  const float* lng = (const float*)d_in[7];
  const float* lnb = (const float*)d_in[8];

  float* out   = (float*)d_out;
  float* attnf = out + (long)BL_ * D_;   // attn output region (B,H,L,L) f32

  char* ws = (char*)d_ws;
  const long MB = 1024 * 1024;
  bf16_t* qbf = (bf16_t*)(ws +   0 * MB);   //  8 MiB
  bf16_t* kbf = (bf16_t*)(ws +   8 * MB);   //  8 MiB
  bf16_t* vbf = (bf16_t*)(ws +  16 * MB);   //  8 MiB
  bf16_t* wqT = (bf16_t*)(ws +  24 * MB);   //  4 MiB  (4096x512)
  bf16_t* wkT = (bf16_t*)(ws +  28 * MB);
  bf16_t* wvT = (bf16_t*)(ws +  32 * MB);
  bf16_t* wfT = (bf16_t*)(ws +  36 * MB);   //  4 MiB  (512x4096)
  bf16_t* qh  = (bf16_t*)(ws +  40 * MB);   // 64 MiB  (8192x4096)
  bf16_t* kh  = (bf16_t*)(ws + 104 * MB);   // 64 MiB
  bf16_t* vh  = (bf16_t*)(ws + 168 * MB);   // 64 MiB
  bf16_t* vhT = (bf16_t*)(ws + 232 * MB);   // 64 MiB  (64 x 512 x 1024)
  bf16_t* abf = qh;                         // 128 MiB, reuses qh+kh after scores
  bf16_t* ctx = vh;                         // 64 MiB,  reuses vh after transpose

  // 1) converts
  const int n4 = BL_ * D_ / 4;
  f2b<<<dim3(n4 / 256), 256, 0, stream>>>((const float4*)q, (bf16x4*)qbf, n4);
  f2b<<<dim3(n4 / 256), 256, 0, stream>>>((const float4*)k, (bf16x4*)kbf, n4);
  f2b<<<dim3(n4 / 256), 256, 0, stream>>>((const float4*)v, (bf16x4*)vbf, n4);
  tconv<<<dim3(HD_ / 32, D_ / 32), dim3(32, 8), 0, stream>>>(wq,  wqT, D_, HD_);
  tconv<<<dim3(HD_ / 32, D_ / 32), dim3(32, 8), 0, stream>>>(wk,  wkT, D_, HD_);
  tconv<<<dim3(HD_ / 32, D_ / 32), dim3(32, 8), 0, stream>>>(wv,  wvT, D_, HD_);
  tconv<<<dim3(D_ / 32, HD_ / 32), dim3(32, 8), 0, stream>>>(wfc, wfT, HD_, D_);

  // 2) projections (qh pre-scaled by 1/sqrt(D))
  const float qscale = 1.0f / sqrtf((float)D_);
  gemm_bt<0><<<dim3(32, 64, 1), 256, 0, stream>>>(qbf, 0, 0, D_, wqT, 0, 0, D_,
                                                  qh, 0, 0, HD_, D_, qscale, nullptr);
  gemm_bt<0><<<dim3(32, 64, 1), 256, 0, stream>>>(kbf, 0, 0, D_, wkT, 0, 0, D_,
                                                  kh, 0, 0, HD_, D_, 1.0f, nullptr);
  gemm_bt<0><<<dim3(32, 64, 1), 256, 0, stream>>>(vbf, 0, 0, D_, wvT, 0, 0, D_,
                                                  vh, 0, 0, HD_, D_, 1.0f, nullptr);

  // 3) vh -> vhT (per (b,h): (L,D) -> (D,L))
  tbf<<<dim3(D_ / 32, L_ / 32, B_ * H_), dim3(32, 8), 0, stream>>>(vh, vhT);

  // 4) scores = qh @ kh^T per (b,h), f32 into attn output region
  gemm_bt<1><<<dim3(8, 8, B_ * H_), 256, 0, stream>>>(
      qh, (long)L_ * HD_, D_, HD_,
      kh, (long)L_ * HD_, D_, HD_,
      attnf, (long)H_ * L_ * L_, (long)L_ * L_, L_, D_, 1.0f, nullptr);

  // 5) softmax in place + bf16 mirror (overwrites qh/kh region)
  softmax_rows<<<dim3(B_ * H_ * L_ / 4), 256, 0, stream>>>(attnf, abf);

  // 6) ctx = attn @ vh per (b,h), bf16 into flat (B*L, H*D)
  gemm_bt<0><<<dim3(4, 8, B_ * H_), 256, 0, stream>>>(
      abf, (long)H_ * L_ * L_, (long)L_ * L_, L_,
      vhT, (long)H_ * D_ * L_, (long)D_ * L_, L_,
      ctx, (long)L_ * HD_, D_, HD_, L_, 1.0f, nullptr);

  // 7) out = ctx @ w_fc + residual(q), f32
  gemm_bt<2><<<dim3(4, 64, 1), 256, 0, stream>>>(
      ctx, 0, 0, HD_, wfT, 0, 0, HD_,
      out, 0, 0, D_, HD_, 1.0f, q);

  // 8) LayerNorm in place
  ln_rows<<<dim3(BL_ / 4), 256, 0, stream>>>(out, lng, lnb);
}